// Round 16
// baseline (266.895 us; speedup 1.0000x reference)
//
#include <hip/hip_runtime.h>
#include <hip/hip_bf16.h>
#include <cstdint>
#include <cstddef>

#define B_ 2
#define T_ 6
#define P_ 10000
#define DIMM 128
#define G0_ 3
#define G1_ 10
#define NTOK 120000
#define NWIN 4000
#define LWIN 30
#define KEXT 160

typedef __attribute__((ext_vector_type(8))) short short8;
typedef __attribute__((ext_vector_type(4))) float f32x4;

__device__ __forceinline__ float frcp_(float x){ return __builtin_amdgcn_rcpf(x); }
__device__ __forceinline__ float fsilu_(float x){ return x*frcp_(1.f+__expf(-x)); }
__device__ __forceinline__ float fsoftplus_(float x){ return (x>15.f)? x : __logf(1.f+__expf(x)); }
__device__ __forceinline__ float geluf_(float x){ return 0.5f*x*(1.f+erff(x*0.70710678118654752f)); }

__device__ __forceinline__ unsigned short bf16bits_(float x){
  union { __hip_bfloat16 h; unsigned short u; } cv; cv.h = __float2bfloat16(x); return cv.u;
}
__device__ __forceinline__ float bits2f_(unsigned short u){
  union { unsigned u; float f; } cv; cv.u = ((unsigned)u)<<16; return cv.f;
}
__device__ __forceinline__ unsigned pkbf16_(float a, float b){
  unsigned r; asm("v_cvt_pk_bf16_f32 %0, %1, %2" : "=v"(r) : "v"(a), "v"(b)); return r;
}

// ================= prep (gather+LN -> A1, xs->bf16 plane) + weight build =================
__global__ __launch_bounds__(256) void k_prep(
    const float* __restrict__ x, const float* __restrict__ xst,
    const int* __restrict__ curves, __hip_bfloat16* __restrict__ A1,
    __hip_bfloat16* __restrict__ xsb,
    const float* __restrict__ ipw, const float* __restrict__ opw,
    const float* __restrict__ f1w, const float* __restrict__ f2w,
    const float* __restrict__ xpw, const float* __restrict__ dtw,
    const float* __restrict__ l1w, const float* __restrict__ l2w,
    const float* __restrict__ l1b, const float* __restrict__ l2b,
    const float* __restrict__ fc1_b, __hip_bfloat16* __restrict__ wbuf)
{
  if (blockIdx.x >= NTOK/4) {
    int i = (blockIdx.x - NTOK/4)*256 + threadIdx.x;
    float* biasf = (float*)(wbuf + 131072);
    if (i >= 131072) {
      int j = i - 131072;
      if (j < 256) {
        float s = 0.f;
        for (int m=0;m<128;m++) s += ipw[j*128+m]*l1b[m];
        biasf[j] = s;
      } else if (j < 384) {
        int n = j - 256;
        float s = fc1_b[n];
        for (int m=0;m<128;m++) s += f1w[n*128+m]*l2b[m];
        biasf[j] = s;
      }
      return;
    }
    float v;
    if (i < 40960) {
      int n = i/KEXT, col = i%KEXT;
      if (col < 128) v = ipw[n*128+col];
      else if (col < 144) { v = 0.f; int j = col-128;
        for (int m=0;m<128;m++) v += ipw[n*128+m]*l1w[m*16+j]; }
      else v = 0.f;
    } else if (i < 57344) v = opw[i-40960];
    else if (i < 77824) {
      int j = i-57344; int n = j/KEXT, col = j%KEXT;
      if (col < 128) v = f1w[n*128+col];
      else if (col < 144) { v = 0.f; int jj = col-128;
        for (int m=0;m<128;m++) v += f1w[n*128+m]*l2w[m*16+jj]; }
      else v = 0.f;
    } else if (i < 94208) v = f2w[i-77824];
    else {
      int j = i - 94208;
      int d = j / 18432;
      int rr = (j >> 7) % 144;
      int k = j & 127;
      if (rr < 128) {
        v = 0.f;
        #pragma unroll
        for (int r=0;r<8;r++) v += dtw[(d*128+rr)*8+r]*xpw[(d*10+r)*128+k];
      } else if (rr == 128) v = xpw[(d*10+8)*128+k];
      else if (rr == 129)  v = xpw[(d*10+9)*128+k];
      else v = 0.f;
    }
    wbuf[i] = __float2bfloat16(v);
    return;
  }
  int token = blockIdx.x*4 + (threadIdx.x>>6);
  int lane = threadIdx.x & 63;
  int b = token/60000, rem = token%60000, t = rem/10000, i = rem%10000;
  int c0 = curves[b*2*P_ + i];
  size_t src = ((size_t)(b*T_+t))*P_ + c0;
  float2 v = *reinterpret_cast<const float2*>(&x[src*128 + lane*2]);
  *reinterpret_cast<unsigned*>(&xsb[(size_t)token*128 + lane*2]) = pkbf16_(v.x, v.y);
  float s = v.x+v.y, q = v.x*v.x+v.y*v.y;
  #pragma unroll
  for (int d=1;d<64;d<<=1){ s += __shfl_xor(s,d); q += __shfl_xor(q,d); }
  float m = s*(1.f/128.f), var = q*(1.f/128.f)-m*m, rs = rsqrtf(var+1e-5f);
  size_t rowb = (size_t)token*KEXT;
  *reinterpret_cast<unsigned*>(&A1[rowb + lane*2]) = pkbf16_((v.x-m)*rs, (v.y-m)*rs);
  if (lane < 16) A1[rowb + 128 + lane] = __float2bfloat16(xst[src*16+lane]);
}

// ========== in_proj GEMM -> split planes: Hx (xh pairs) / Hz (silu(z) pairs) ==========
__global__ __launch_bounds__(256) void k_gemm_in(
    const __hip_bfloat16* __restrict__ A, const __hip_bfloat16* __restrict__ Wb,
    const float* __restrict__ bias,
    unsigned short* __restrict__ Hx, unsigned short* __restrict__ Hz)
{
  __shared__ __hip_bfloat16 As[96][168];
  __shared__ __hip_bfloat16 Bs[128][168];
  const int tid = threadIdx.x;
  const size_t m0 = (size_t)blockIdx.x * 96;
  const int n0 = blockIdx.y * 128;
  #pragma unroll
  for (int p = 0; p < 8; ++p) {
    int ch = tid + p*256;
    if (ch < 1920) {
      int r = ch/20, c8 = ch%20;
      *reinterpret_cast<uint4*>(&As[r][c8*8]) =
        *reinterpret_cast<const uint4*>(&A[(m0 + r)*KEXT + c8*8]);
    }
  }
  #pragma unroll
  for (int p = 0; p < 10; ++p) {
    int ch = tid + p*256;
    int r = ch/20, c8 = ch%20;
    *reinterpret_cast<uint4*>(&Bs[r][c8*8]) =
      *reinterpret_cast<const uint4*>(&Wb[(size_t)(n0 + r)*KEXT + c8*8]);
  }
  __syncthreads();
  const int wave = tid >> 6, lane = tid & 63;
  const int rb = (wave >> 1) * 48, cb = (wave & 1) * 64;
  const int lrow = lane & 15, koff = (lane >> 4) * 8;
  f32x4 acc[3][4];
  #pragma unroll
  for (int i=0;i<3;i++)
    #pragma unroll
    for (int j=0;j<4;j++) acc[i][j] = f32x4{0.f,0.f,0.f,0.f};
  #pragma unroll
  for (int kb = 0; kb < 5; ++kb) {
    short8 a[3], bf[4];
    #pragma unroll
    for (int i=0;i<3;i++) a[i] = *reinterpret_cast<const short8*>(&As[rb + i*16 + lrow][kb*32 + koff]);
    #pragma unroll
    for (int j=0;j<4;j++) bf[j] = *reinterpret_cast<const short8*>(&Bs[cb + j*16 + lrow][kb*32 + koff]);
    #pragma unroll
    for (int i=0;i<3;i++)
      #pragma unroll
      for (int j=0;j<4;j++)
        acc[i][j] = __builtin_amdgcn_mfma_f32_16x16x32_bf16(a[i], bf[j], acc[i][j], 0,0,0);
  }
  const int crow0 = (lane >> 4) * 4, ccol = lane & 15;
  const int isz = blockIdx.y;
  unsigned short* Hp = isz ? Hz : Hx;
  #pragma unroll
  for (int i=0;i<3;i++)
    #pragma unroll
    for (int j=0;j<4;j++){
      int n = n0 + cb + j*16 + ccol;
      int col = n & 127;
      float bv = bias[n];
      #pragma unroll
      for (int r=0;r<4;r++){
        size_t m = m0 + rb + i*16 + crow0 + r;
        float v = acc[i][j][r] + bv;
        if (isz) v = fsilu_(v);           // Hz stores silu(z)
        Hp[(m*64 + (col&63))*2 + (col>>6)] = bf16bits_(v);
      }
    }
}

// ======= fused conv + xproj(MFMA) + scan: 4 waves / block, fwd/bwd PAIRED on same CU =======
__global__ __launch_bounds__(256) void k_scan(
    const unsigned* __restrict__ Hx,
    const float* __restrict__ conv_w, const float* __restrict__ conv_b,
    const __hip_bfloat16* __restrict__ Wbig,
    const float* __restrict__ dt_b, const float* __restrict__ A_log,
    const float* __restrict__ Dp,
    unsigned* __restrict__ Y)
{
  const int ws_ = threadIdx.x >> 6;
  const int ln  = threadIdx.x & 63;
  const int pair = blockIdx.x*2 + (ws_>>1);
  const int dir  = ws_ & 1;
  const int ba   = pair / 1000;
  const int q    = pair % 1000;
  const int qw   = dir ? (999 - q) : q;
  const int n    = ba*1000 + qw;
  const int b  = ba >> 1;
  const int a  = ba & 1;
  const int qw10 = qw*G1_;
  const int row0 = (b*T_ + a*G0_)*P_;

  __shared__ __align__(16) char smem_[4][8832];
  __hip_bfloat16 (*u_lds)[136] = (__hip_bfloat16 (*)[136])smem_[ws_];
  unsigned* es16 = (unsigned*)smem_[ws_];
  float* Bs_ = (float*)(smem_[ws_] + 8576);
  float* Cs_ = Bs_ + 32;

  float w0a = conv_w[(dir*DIMM + ln)*3+0],   w1a = conv_w[(dir*DIMM + ln)*3+1];
  float w2a = conv_w[(dir*DIMM + ln)*3+2],   cba = conv_b[dir*DIMM + ln];
  float w0b = conv_w[(dir*DIMM + ln+64)*3+0],w1b = conv_w[(dir*DIMM + ln+64)*3+1];
  float w2b = conv_w[(dir*DIMM + ln+64)*3+2],cbb = conv_b[dir*DIMM + ln+64];
  float xm1a=0.f, xm2a=0.f, xm1b=0.f, xm2b=0.f;
  unsigned upk[LWIN];
  #pragma unroll
  for (int l=0;l<LWIN;l++){
    int pf = qw10 + l%G1_;
    int p  = dir ? (P_-1-pf) : pf;
    size_t row = (size_t)(row0 + (l/G1_)*P_ + p);
    unsigned v = Hx[row*64 + ln];
    float xa = bits2f_((unsigned short)(v & 0xffffu));
    float xb = bits2f_((unsigned short)(v >> 16));
    float ua = fsilu_(w0a*xm2a + w1a*xm1a + w2a*xa + cba); xm2a=xm1a; xm1a=xa;
    float ub = fsilu_(w0b*xm2b + w1b*xm1b + w2b*xb + cbb); xm2b=xm1b; xm1b=xb;
    unsigned w = pkbf16_(ua, ub);
    upk[l] = w;
    *(unsigned short*)&u_lds[l][ln]    = (unsigned short)(w & 0xffffu);
    *(unsigned short*)&u_lds[l][ln+64] = (unsigned short)(w >> 16);
  }
  *(unsigned short*)&u_lds[30][ln] = 0; *(unsigned short*)&u_lds[30][ln+64] = 0;
  *(unsigned short*)&u_lds[31][ln] = 0; *(unsigned short*)&u_lds[31][ln+64] = 0;

  const int lrow = ln & 15, koff = (ln >> 4) * 8;
  const __hip_bfloat16* Wd = Wbig + (size_t)dir*144*128;
  f32x4 acc[2][9];
  #pragma unroll
  for (int rg=0;rg<2;rg++)
    #pragma unroll
    for (int t=0;t<9;t++) acc[rg][t] = f32x4{0.f,0.f,0.f,0.f};
  #pragma unroll
  for (int kb=0; kb<4; ++kb){
    short8 av0 = *reinterpret_cast<const short8*>(&u_lds[lrow][kb*32 + koff]);
    short8 av1 = *reinterpret_cast<const short8*>(&u_lds[16 + lrow][kb*32 + koff]);
    #pragma unroll
    for (int t=0;t<9;t++){
      short8 bv = *reinterpret_cast<const short8*>(&Wd[(size_t)(t*16 + lrow)*128 + kb*32 + koff]);
      acc[0][t] = __builtin_amdgcn_mfma_f32_16x16x32_bf16(av0, bv, acc[0][t], 0,0,0);
      acc[1][t] = __builtin_amdgcn_mfma_f32_16x16x32_bf16(av1, bv, acc[1][t], 0,0,0);
    }
  }

  float dtbj[8], Avj[8];
  #pragma unroll
  for (int t=0;t<8;t++){
    int j = t*16 + lrow;
    dtbj[t] = dt_b[dir*128 + j];
    Avj[t]  = -__expf(A_log[dir*128 + j]);
  }
  float Dv0 = Dp[dir*DIMM + ln], Dv1 = Dp[dir*DIMM + ln+64];
  float h0 = 0.f, h1 = 0.f;
  unsigned* Yp = Y + ((size_t)dir*NWIN + n)*LWIN*64;
  const int loc = (ln>>4)*4;

  #pragma unroll
  for (int rg=0; rg<2; ++rg){
    #pragma unroll
    for (int t=0;t<8;t++){
      int j = t*16 + lrow;
      int wbase = ((j&63)<<1) + (j>>6);
      #pragma unroll
      for (int r=0;r<4;r++){
        float d  = fsoftplus_(acc[rg][t][r] + dtbj[t]);
        float dA = __expf(d*Avj[t]);
        es16[(loc+r)*134 + wbase] = pkbf16_(d, dA);
      }
    }
    if (lrow == 0){
      #pragma unroll
      for (int r=0;r<4;r++) Bs_[rg*16 + loc + r] = acc[rg][8][r];
    } else if (lrow == 1){
      #pragma unroll
      for (int r=0;r<4;r++) Cs_[rg*16 + loc + r] = acc[rg][8][r];
    }
    const int lst = rg*16, len = rg ? 14 : 16;
    const uint2* esr = (const uint2*)es16;
    for (int li=0; li<len; ++li){
      int l = lst + li;
      uint2 e = esr[li*67 + ln];
      float Bl = Bs_[l], Cl = Cs_[l];
      float u0 = bits2f_((unsigned short)(upk[l] & 0xffffu));
      float u1 = bits2f_((unsigned short)(upk[l] >> 16));
      float dl0 = bits2f_((unsigned short)(e.x & 0xffffu)), dA0 = bits2f_((unsigned short)(e.x >> 16));
      float dl1 = bits2f_((unsigned short)(e.y & 0xffffu)), dA1 = bits2f_((unsigned short)(e.y >> 16));
      h0 = fmaf(dA0, h0, dl0*u0*Bl);
      h1 = fmaf(dA1, h1, dl1*u1*Bl);
      float y0 = fmaf(h0, Cl, u0*Dv0);
      float y1 = fmaf(h1, Cl, u1*Dv1);
      Yp[l*64 + ln] = pkbf16_(y0, y1);
    }
  }
}

// ================= _wrev scramble index =================
__device__ __forceinline__ int win_index(int t, int p){
  int G  = t*P_ + p;
  int d3 = G / 6000;
  int r  = G % 6000;
  int d1 = r / 6;
  int r2 = r % 6;
  int d4 = r2 >> 1;
  int d2 = r2 & 1;
  int F  = d1*60 + d2*30 + d3*3 + d4;
  int a  = F / 30000;
  int F2 = F % 30000;
  int qw = F2 / 30;
  int l  = F2 % 30;
  return (a*1000 + qw)*LWIN + l;
}

// ========== out_proj GEMM: A = 0.5*(Yf+Yb_gathered)*sz (pre-silu'd Hz) ; bf16 out ==========
__global__ __launch_bounds__(256) void k_gemm_out(
    const unsigned* __restrict__ Y32, const unsigned* __restrict__ Hz32,
    const __hip_bfloat16* __restrict__ Wb, __hip_bfloat16* __restrict__ yproj)
{
  __shared__ __hip_bfloat16 As[96][136];
  __shared__ __hip_bfloat16 Bs[128][136];
  const int tid = threadIdx.x;
  const size_t m0 = (size_t)blockIdx.x * 96;
  const unsigned* Yb32 = Y32 + (size_t)NWIN*LWIN*64;
  #pragma unroll
  for (int p = 0; p < 6; ++p) {
    int ch = tid + p*256; int r = ch >> 4, c16 = ch & 15;
    int token = (int)m0 + r;
    int b = token/60000, rem = token%60000, t = rem/10000, pp = rem%10000;
    size_t bbase = (size_t)b*60000;
    int wf = win_index(t, pp), wb = win_index(t, P_-1-pp);
    uint4 hzv = *reinterpret_cast<const uint4*>(&Hz32[(size_t)token*64 + c16*4]);
    uint4 fv = *reinterpret_cast<const uint4*>(&Y32 [(bbase+wf)*64 + c16*4]);
    uint4 gv = *reinterpret_cast<const uint4*>(&Yb32[(bbase+wb)*64 + c16*4]);
    const unsigned* hz = reinterpret_cast<const unsigned*>(&hzv);
    const unsigned* fu = reinterpret_cast<const unsigned*>(&fv);
    const unsigned* gu = reinterpret_cast<const unsigned*>(&gv);
    unsigned short lo[4], hi[4];
    #pragma unroll
    for (int k=0;k<4;k++){
      float zl = bits2f_((unsigned short)(hz[k] & 0xffffu));
      float zh = bits2f_((unsigned short)(hz[k] >> 16));
      float fl = bits2f_((unsigned short)(fu[k] & 0xffffu));
      float fh = bits2f_((unsigned short)(fu[k] >> 16));
      float gl = bits2f_((unsigned short)(gu[k] & 0xffffu));
      float gh = bits2f_((unsigned short)(gu[k] >> 16));
      lo[k] = bf16bits_(0.5f*(fl+gl)*zl);
      hi[k] = bf16bits_(0.5f*(fh+gh)*zh);
    }
    unsigned oL[2] = { (((unsigned)lo[1])<<16)|lo[0], (((unsigned)lo[3])<<16)|lo[2] };
    unsigned oH[2] = { (((unsigned)hi[1])<<16)|hi[0], (((unsigned)hi[3])<<16)|hi[2] };
    *reinterpret_cast<uint2*>(&As[r][c16*4])      = *reinterpret_cast<uint2*>(oL);
    *reinterpret_cast<uint2*>(&As[r][64 + c16*4]) = *reinterpret_cast<uint2*>(oH);
  }
  #pragma unroll
  for (int p = 0; p < 8; ++p) {
    int ch = tid + p*256; int r = ch >> 4, c16 = ch & 15;
    *reinterpret_cast<uint4*>(&Bs[r][c16*8]) =
      *reinterpret_cast<const uint4*>(&Wb[(size_t)r*128 + c16*8]);
  }
  __syncthreads();
  const int wave = tid >> 6, lane = tid & 63;
  const int rb = (wave >> 1) * 48, cb = (wave & 1) * 64;
  const int lrow = lane & 15, koff = (lane >> 4) * 8;
  f32x4 acc[3][4];
  #pragma unroll
  for (int i=0;i<3;i++)
    #pragma unroll
    for (int j=0;j<4;j++) acc[i][j] = f32x4{0.f,0.f,0.f,0.f};
  #pragma unroll
  for (int kb = 0; kb < 4; ++kb) {
    short8 a[3], bf[4];
    #pragma unroll
    for (int i=0;i<3;i++) a[i] = *reinterpret_cast<const short8*>(&As[rb + i*16 + lrow][kb*32 + koff]);
    #pragma unroll
    for (int j=0;j<4;j++) bf[j] = *reinterpret_cast<const short8*>(&Bs[cb + j*16 + lrow][kb*32 + koff]);
    #pragma unroll
    for (int i=0;i<3;i++)
      #pragma unroll
      for (int j=0;j<4;j++)
        acc[i][j] = __builtin_amdgcn_mfma_f32_16x16x32_bf16(a[i], bf[j], acc[i][j], 0,0,0);
  }
  const int crow0 = (lane >> 4) * 4, ccol = lane & 15;
  #pragma unroll
  for (int i=0;i<3;i++)
    #pragma unroll
    for (int j=0;j<4;j++){
      int nn = cb + j*16 + ccol;
      #pragma unroll
      for (int r=0;r<4;r++){
        size_t m = m0 + rb + i*16 + crow0 + r;
        yproj[m*128 + nn] = __float2bfloat16(acc[i][j][r]);
      }
    }
}

// ===== mid: x1 = xsb + yproj (bf16, coalesced reads) ; A2 = [LN(x1)|ss|·] =====
__global__ __launch_bounds__(256) void k_mid(
    const __hip_bfloat16* __restrict__ xsb, const float* __restrict__ xst,
    const int* __restrict__ curves, const __hip_bfloat16* __restrict__ yproj,
    __hip_bfloat16* __restrict__ x1, __hip_bfloat16* __restrict__ A2)
{
  int token = blockIdx.x*4 + (threadIdx.x>>6);
  int lane = threadIdx.x & 63;
  unsigned xw = *reinterpret_cast<const unsigned*>(&xsb[(size_t)token*128 + lane*2]);
  __hip_bfloat162 yp = *reinterpret_cast<const __hip_bfloat162*>(&yproj[(size_t)token*128 + lane*2]);
  float2 v;
  v.x = bits2f_((unsigned short)(xw & 0xffffu)) + __bfloat162float(yp.x);
  v.y = bits2f_((unsigned short)(xw >> 16))     + __bfloat162float(yp.y);
  *reinterpret_cast<unsigned*>(&x1[(size_t)token*128 + lane*2]) = pkbf16_(v.x, v.y);
  float s = v.x+v.y, q = v.x*v.x+v.y*v.y;
  #pragma unroll
  for (int d=1;d<64;d<<=1){ s += __shfl_xor(s,d); q += __shfl_xor(q,d); }
  float m = s*(1.f/128.f), var = q*(1.f/128.f)-m*m, rs = rsqrtf(var+1e-5f);
  size_t rowb = (size_t)token*KEXT;
  *reinterpret_cast<unsigned*>(&A2[rowb + lane*2]) = pkbf16_((v.x-m)*rs, (v.y-m)*rs);
  if (lane < 16) {
    int b = token/60000, rem = token%60000, t = rem/10000, i = rem%10000;
    int c0 = curves[b*2*P_ + i];
    size_t src = ((size_t)(b*T_+t))*P_ + c0;
    A2[rowb + 128 + lane] = __float2bfloat16(xst[src*16+lane]);
  }
}

// ================= fused MLP: x2 = bf16(x1 + fc2(gelu(fc1e(A2)))) =================
__global__ __launch_bounds__(256) void k_gemm_mlp(
    const __hip_bfloat16* __restrict__ A, const __hip_bfloat16* __restrict__ W1e,
    const __hip_bfloat16* __restrict__ W2,
    const float* __restrict__ b1e, const float* __restrict__ b2,
    const __hip_bfloat16* __restrict__ x1, __hip_bfloat16* __restrict__ x2)
{
  __shared__ __hip_bfloat16 As[96][168];
  __shared__ __hip_bfloat16 Bs[128][168];
  const int tid = threadIdx.x;
  const size_t m0 = (size_t)blockIdx.x * 96;
  #pragma unroll
  for (int p = 0; p < 8; ++p) {
    int ch = tid + p*256;
    if (ch < 1920) {
      int r = ch/20, c8 = ch%20;
      *reinterpret_cast<uint4*>(&As[r][c8*8]) =
        *reinterpret_cast<const uint4*>(&A[(m0 + r)*KEXT + c8*8]);
    }
  }
  #pragma unroll
  for (int p = 0; p < 10; ++p) {
    int ch = tid + p*256;
    int r = ch/20, c8 = ch%20;
    *reinterpret_cast<uint4*>(&Bs[r][c8*8]) =
      *reinterpret_cast<const uint4*>(&W1e[(size_t)r*KEXT + c8*8]);
  }
  __syncthreads();
  const int wave = tid >> 6, lane = tid & 63;
  const int rb = (wave >> 1) * 48, cb = (wave & 1) * 64;
  const int lrow = lane & 15, koff = (lane >> 4) * 8;
  const int crow0 = (lane >> 4) * 4, ccol = lane & 15;
  f32x4 acc[3][4];
  #pragma unroll
  for (int i=0;i<3;i++)
    #pragma unroll
    for (int j=0;j<4;j++) acc[i][j] = f32x4{0.f,0.f,0.f,0.f};
  #pragma unroll
  for (int kb = 0; kb < 5; ++kb) {
    short8 a[3], bf[4];
    #pragma unroll
    for (int i=0;i<3;i++) a[i] = *reinterpret_cast<const short8*>(&As[rb + i*16 + lrow][kb*32 + koff]);
    #pragma unroll
    for (int j=0;j<4;j++) bf[j] = *reinterpret_cast<const short8*>(&Bs[cb + j*16 + lrow][kb*32 + koff]);
    #pragma unroll
    for (int i=0;i<3;i++)
      #pragma unroll
      for (int j=0;j<4;j++)
        acc[i][j] = __builtin_amdgcn_mfma_f32_16x16x32_bf16(a[i], bf[j], acc[i][j], 0,0,0);
  }
  __syncthreads();
  #pragma unroll
  for (int i=0;i<3;i++)
    #pragma unroll
    for (int j=0;j<4;j++){
      int nn = cb + j*16 + ccol;
      float bv = b1e[nn];
      #pragma unroll
      for (int r=0;r<4;r++){
        int row = rb + i*16 + crow0 + r;
        As[row][nn] = __float2bfloat16(geluf_(acc[i][j][r] + bv));
      }
    }
  #pragma unroll
  for (int p = 0; p < 8; ++p) {
    int ch = tid + p*256; int r = ch >> 4, c16 = ch & 15;
    *reinterpret_cast<uint4*>(&Bs[r][c16*8]) =
      *reinterpret_cast<const uint4*>(&W2[(size_t)r*128 + c16*8]);
  }
  __syncthreads();
  #pragma unroll
  for (int i=0;i<3;i++)
    #pragma unroll
    for (int j=0;j<4;j++) acc[i][j] = f32x4{0.f,0.f,0.f,0.f};
  #pragma unroll
  for (int kb = 0; kb < 4; ++kb) {
    short8 a[3], bf[4];
    #pragma unroll
    for (int i=0;i<3;i++) a[i] = *reinterpret_cast<const short8*>(&As[rb + i*16 + lrow][kb*32 + koff]);
    #pragma unroll
    for (int j=0;j<4;j++) bf[j] = *reinterpret_cast<const short8*>(&Bs[cb + j*16 + lrow][kb*32 + koff]);
    #pragma unroll
    for (int i=0;i<3;i++)
      #pragma unroll
      for (int j=0;j<4;j++)
        acc[i][j] = __builtin_amdgcn_mfma_f32_16x16x32_bf16(a[i], bf[j], acc[i][j], 0,0,0);
  }
  #pragma unroll
  for (int i=0;i<3;i++)
    #pragma unroll
    for (int j=0;j<4;j++){
      int nn = cb + j*16 + ccol;
      float bv = b2[nn];
      #pragma unroll
      for (int r=0;r<4;r++){
        size_t m = m0 + rb + i*16 + crow0 + r;
        x2[m*128 + nn] = __float2bfloat16(acc[i][j][r] + bv + __bfloat162float(x1[m*128 + nn]));
      }
    }
}

// ================= final: gather x2 by c1 -> f32 out =================
__global__ __launch_bounds__(256) void k_final(
    const __hip_bfloat16* __restrict__ x2, const int* __restrict__ curves,
    float* __restrict__ out)
{
  int token = blockIdx.x*4 + (threadIdx.x>>6);
  int lane = threadIdx.x & 63;
  int b = token/60000, rem = token%60000, t = rem/10000, i = rem%10000;
  int c1 = curves[(b*2+1)*P_ + i];
  size_t src = ((size_t)(b*T_+t))*P_ + c1;
  __hip_bfloat162 v = *reinterpret_cast<const __hip_bfloat162*>(&x2[src*128 + lane*2]);
  float2 o; o.x = __bfloat162float(v.x); o.y = __bfloat162float(v.y);
  *reinterpret_cast<float2*>(&out[(size_t)token*128 + lane*2]) = o;
}

extern "C" void kernel_launch(void* const* d_in, const int* in_sizes, int n_in,
                              void* d_out, int out_size, void* d_ws, size_t ws_size,
                              hipStream_t stream) {
  const float* x        = (const float*)d_in[0];
  const float* xst      = (const float*)d_in[1];
  const int*   curves   = (const int*)  d_in[2];
  const float* loan1_w  = (const float*)d_in[3];
  const float* loan1_b  = (const float*)d_in[4];
  const float* loan2_w  = (const float*)d_in[5];
  const float* loan2_b  = (const float*)d_in[6];
  const float* in_proj_w  = (const float*)d_in[7];
  const float* out_proj_w = (const float*)d_in[8];
  const float* conv_w   = (const float*)d_in[9];
  const float* conv_b   = (const float*)d_in[10];
  const float* xproj_w  = (const float*)d_in[11];
  const float* dt_w     = (const float*)d_in[12];
  const float* dt_b     = (const float*)d_in[13];
  const float* A_log    = (const float*)d_in[14];
  const float* Dvec     = (const float*)d_in[15];
  const float* fc1_w    = (const float*)d_in[16];
  const float* fc1_b    = (const float*)d_in[17];
  const float* fc2_w    = (const float*)d_in[18];
  const float* fc2_b    = (const float*)d_in[19];
  float* out = (float*)d_out;

  char* ws = (char*)d_ws;
  // [0,61.44M):        Y32 -> x1 bf16 [0,30.72M)
  // [61.44M,92.16M):   Hx -> yproj bf16
  // [92.16M,122.88M):  Hz(silu) -> x2 bf16
  // [122.88M,161.28M): A1 -> A2
  // [161.28M,161.55M): weights
  // [162M,192.72M):    xsb (gathered x, bf16; live prep->mid)
  unsigned*       Ybuf = (unsigned*)(ws + 0);
  __hip_bfloat16* x1   = (__hip_bfloat16*)(ws + 0);
  unsigned*       Hx   = (unsigned*)(ws + 61440000);
  __hip_bfloat16* yproj= (__hip_bfloat16*)(ws + 61440000);
  unsigned*       Hz   = (unsigned*)(ws + 92160000);
  __hip_bfloat16* x2   = (__hip_bfloat16*)(ws + 92160000);
  __hip_bfloat16* A1   = (__hip_bfloat16*)(ws + 122880000);
  __hip_bfloat16* A2   = (__hip_bfloat16*)(ws + 122880000);
  __hip_bfloat16* wbuf = (__hip_bfloat16*)(ws + 161280000);
  __hip_bfloat16* xsb  = (__hip_bfloat16*)(ws + 162000000);
  __hip_bfloat16* ipw_e  = wbuf;
  __hip_bfloat16* opw_bf = wbuf + 40960;
  __hip_bfloat16* f1w_e  = wbuf + 57344;
  __hip_bfloat16* f2w_bf = wbuf + 77824;
  __hip_bfloat16* Wbig   = wbuf + 94208;
  float* biasf = (float*)(wbuf + 131072);
  float* bias_in = biasf;
  float* bias_f1 = biasf + 256;

  k_prep<<<NTOK/4 + 514, 256, 0, stream>>>(x, xst, curves, A1, xsb,
      in_proj_w, out_proj_w, fc1_w, fc2_w, xproj_w, dt_w,
      loan1_w, loan2_w, loan1_b, loan2_b, fc1_b, wbuf);

  dim3 g1(NTOK/96, 2);
  k_gemm_in<<<g1, 256, 0, stream>>>(A1, ipw_e, bias_in,
                                    (unsigned short*)Hx, (unsigned short*)Hz);

  k_scan<<<2000, 256, 0, stream>>>(Hx, conv_w, conv_b, Wbig, dt_b, A_log, Dvec, Ybuf);

  k_gemm_out<<<NTOK/96, 256, 0, stream>>>(Ybuf, Hz, opw_bf, yproj);

  k_mid<<<NTOK/4, 256, 0, stream>>>(xsb, xst, curves, yproj, x1, A2);

  k_gemm_mlp<<<NTOK/96, 256, 0, stream>>>(A2, f1w_e, f2w_bf, bias_f1, fc2_b, x1, x2);

  k_final<<<NTOK/4, 256, 0, stream>>>(x2, curves, out);
}

// Round 17
// 250.049 us; speedup vs baseline: 1.0674x; 1.0674x over previous
//
#include <hip/hip_runtime.h>
#include <hip/hip_bf16.h>
#include <cstdint>
#include <cstddef>

#define B_ 2
#define T_ 6
#define P_ 10000
#define DIMM 128
#define G0_ 3
#define G1_ 10
#define NTOK 120000
#define NWIN 4000
#define LWIN 30
#define KEXT 160

typedef __attribute__((ext_vector_type(8))) short short8;
typedef __attribute__((ext_vector_type(4))) float f32x4;

__device__ __forceinline__ float frcp_(float x){ return __builtin_amdgcn_rcpf(x); }
__device__ __forceinline__ float fsilu_(float x){ return x*frcp_(1.f+__expf(-x)); }
__device__ __forceinline__ float fsoftplus_(float x){ return (x>15.f)? x : __logf(1.f+__expf(x)); }
__device__ __forceinline__ float geluf_(float x){ return 0.5f*x*(1.f+erff(x*0.70710678118654752f)); }

__device__ __forceinline__ unsigned short bf16bits_(float x){
  union { __hip_bfloat16 h; unsigned short u; } cv; cv.h = __float2bfloat16(x); return cv.u;
}
__device__ __forceinline__ float bits2f_(unsigned short u){
  union { unsigned u; float f; } cv; cv.u = ((unsigned)u)<<16; return cv.f;
}
__device__ __forceinline__ unsigned pkbf16_(float a, float b){
  unsigned r; asm("v_cvt_pk_bf16_f32 %0, %1, %2" : "=v"(r) : "v"(a), "v"(b)); return r;
}

// ================= prep (gather+LN -> A1) + weight build (tail blocks) =================
__global__ __launch_bounds__(256) void k_prep(
    const float* __restrict__ x, const float* __restrict__ xst,
    const int* __restrict__ curves, __hip_bfloat16* __restrict__ A1,
    const float* __restrict__ ipw, const float* __restrict__ opw,
    const float* __restrict__ f1w, const float* __restrict__ f2w,
    const float* __restrict__ xpw, const float* __restrict__ dtw,
    const float* __restrict__ l1w, const float* __restrict__ l2w,
    const float* __restrict__ l1b, const float* __restrict__ l2b,
    const float* __restrict__ fc1_b, __hip_bfloat16* __restrict__ wbuf)
{
  if (blockIdx.x >= NTOK/4) {
    int i = (blockIdx.x - NTOK/4)*256 + threadIdx.x;
    float* biasf = (float*)(wbuf + 131072);
    if (i >= 131072) {
      int j = i - 131072;
      if (j < 256) {
        float s = 0.f;
        for (int m=0;m<128;m++) s += ipw[j*128+m]*l1b[m];
        biasf[j] = s;
      } else if (j < 384) {
        int n = j - 256;
        float s = fc1_b[n];
        for (int m=0;m<128;m++) s += f1w[n*128+m]*l2b[m];
        biasf[j] = s;
      }
      return;
    }
    float v;
    if (i < 40960) {
      int n = i/KEXT, col = i%KEXT;
      if (col < 128) v = ipw[n*128+col];
      else if (col < 144) { v = 0.f; int j = col-128;
        for (int m=0;m<128;m++) v += ipw[n*128+m]*l1w[m*16+j]; }
      else v = 0.f;
    } else if (i < 57344) v = opw[i-40960];
    else if (i < 77824) {
      int j = i-57344; int n = j/KEXT, col = j%KEXT;
      if (col < 128) v = f1w[n*128+col];
      else if (col < 144) { v = 0.f; int jj = col-128;
        for (int m=0;m<128;m++) v += f1w[n*128+m]*l2w[m*16+jj]; }
      else v = 0.f;
    } else if (i < 94208) v = f2w[i-77824];
    else {
      int j = i - 94208;
      int d = j / 18432;
      int rr = (j >> 7) % 144;
      int k = j & 127;
      if (rr < 128) {
        v = 0.f;
        #pragma unroll
        for (int r=0;r<8;r++) v += dtw[(d*128+rr)*8+r]*xpw[(d*10+r)*128+k];
      } else if (rr == 128) v = xpw[(d*10+8)*128+k];
      else if (rr == 129)  v = xpw[(d*10+9)*128+k];
      else v = 0.f;
    }
    wbuf[i] = __float2bfloat16(v);
    return;
  }
  int token = blockIdx.x*4 + (threadIdx.x>>6);
  int lane = threadIdx.x & 63;
  int b = token/60000, rem = token%60000, t = rem/10000, i = rem%10000;
  int c0 = curves[b*2*P_ + i];
  size_t src = ((size_t)(b*T_+t))*P_ + c0;
  float2 v = *reinterpret_cast<const float2*>(&x[src*128 + lane*2]);
  float s = v.x+v.y, q = v.x*v.x+v.y*v.y;
  #pragma unroll
  for (int d=1;d<64;d<<=1){ s += __shfl_xor(s,d); q += __shfl_xor(q,d); }
  float m = s*(1.f/128.f), var = q*(1.f/128.f)-m*m, rs = rsqrtf(var+1e-5f);
  size_t rowb = (size_t)token*KEXT;
  *reinterpret_cast<unsigned*>(&A1[rowb + lane*2]) = pkbf16_((v.x-m)*rs, (v.y-m)*rs);
  if (lane < 16) A1[rowb + 128 + lane] = __float2bfloat16(xst[src*16+lane]);
}

// ========== in_proj GEMM -> split planes: Hx (xh pairs) / Hz (z pairs) ==========
__global__ __launch_bounds__(256) void k_gemm_in(
    const __hip_bfloat16* __restrict__ A, const __hip_bfloat16* __restrict__ Wb,
    const float* __restrict__ bias,
    unsigned short* __restrict__ Hx, unsigned short* __restrict__ Hz)
{
  __shared__ __hip_bfloat16 As[96][168];
  __shared__ __hip_bfloat16 Bs[128][168];
  const int tid = threadIdx.x;
  const size_t m0 = (size_t)blockIdx.x * 96;
  const int n0 = blockIdx.y * 128;
  #pragma unroll
  for (int p = 0; p < 8; ++p) {
    int ch = tid + p*256;
    if (ch < 1920) {
      int r = ch/20, c8 = ch%20;
      *reinterpret_cast<uint4*>(&As[r][c8*8]) =
        *reinterpret_cast<const uint4*>(&A[(m0 + r)*KEXT + c8*8]);
    }
  }
  #pragma unroll
  for (int p = 0; p < 10; ++p) {
    int ch = tid + p*256;
    int r = ch/20, c8 = ch%20;
    *reinterpret_cast<uint4*>(&Bs[r][c8*8]) =
      *reinterpret_cast<const uint4*>(&Wb[(size_t)(n0 + r)*KEXT + c8*8]);
  }
  __syncthreads();
  const int wave = tid >> 6, lane = tid & 63;
  const int rb = (wave >> 1) * 48, cb = (wave & 1) * 64;
  const int lrow = lane & 15, koff = (lane >> 4) * 8;
  f32x4 acc[3][4];
  #pragma unroll
  for (int i=0;i<3;i++)
    #pragma unroll
    for (int j=0;j<4;j++) acc[i][j] = f32x4{0.f,0.f,0.f,0.f};
  #pragma unroll
  for (int kb = 0; kb < 5; ++kb) {
    short8 a[3], bf[4];
    #pragma unroll
    for (int i=0;i<3;i++) a[i] = *reinterpret_cast<const short8*>(&As[rb + i*16 + lrow][kb*32 + koff]);
    #pragma unroll
    for (int j=0;j<4;j++) bf[j] = *reinterpret_cast<const short8*>(&Bs[cb + j*16 + lrow][kb*32 + koff]);
    #pragma unroll
    for (int i=0;i<3;i++)
      #pragma unroll
      for (int j=0;j<4;j++)
        acc[i][j] = __builtin_amdgcn_mfma_f32_16x16x32_bf16(a[i], bf[j], acc[i][j], 0,0,0);
  }
  const int crow0 = (lane >> 4) * 4, ccol = lane & 15;
  unsigned short* Hp = blockIdx.y ? Hz : Hx;
  #pragma unroll
  for (int i=0;i<3;i++)
    #pragma unroll
    for (int j=0;j<4;j++){
      int n = n0 + cb + j*16 + ccol;
      int col = n & 127;
      float bv = bias[n];
      #pragma unroll
      for (int r=0;r<4;r++){
        size_t m = m0 + rb + i*16 + crow0 + r;
        Hp[(m*64 + (col&63))*2 + (col>>6)] = bf16bits_(acc[i][j][r] + bv);
      }
    }
}

// ======= fused conv + xproj(MFMA) + scan: 4 waves / block, fwd/bwd PAIRED on same CU =======
// Waves in a block: {fwd(q), bwd(999-q), fwd(q+1), bwd(998-q)} — partner waves read the
// SAME 30 Hx rows, so the second becomes an L1/L2 hit.
__global__ __launch_bounds__(256) void k_scan(
    const unsigned* __restrict__ Hx,
    const float* __restrict__ conv_w, const float* __restrict__ conv_b,
    const __hip_bfloat16* __restrict__ Wbig,
    const float* __restrict__ dt_b, const float* __restrict__ A_log,
    const float* __restrict__ Dp,
    unsigned* __restrict__ Y)
{
  const int ws_ = threadIdx.x >> 6;
  const int ln  = threadIdx.x & 63;
  const int pair = blockIdx.x*2 + (ws_>>1);   // [0,4000)
  const int dir  = ws_ & 1;
  const int ba   = pair / 1000;               // b*2+a
  const int q    = pair % 1000;
  const int qw   = dir ? (999 - q) : q;       // window's own qw index
  const int n    = ba*1000 + qw;
  const int b  = ba >> 1;
  const int a  = ba & 1;
  const int qw10 = qw*G1_;
  const int row0 = (b*T_ + a*G0_)*P_;

  __shared__ __align__(16) char smem_[4][8832];
  __hip_bfloat16 (*u_lds)[136] = (__hip_bfloat16 (*)[136])smem_[ws_];
  unsigned* es16 = (unsigned*)smem_[ws_];
  float* Bs_ = (float*)(smem_[ws_] + 8576);
  float* Cs_ = Bs_ + 32;

  float w0a = conv_w[(dir*DIMM + ln)*3+0],   w1a = conv_w[(dir*DIMM + ln)*3+1];
  float w2a = conv_w[(dir*DIMM + ln)*3+2],   cba = conv_b[dir*DIMM + ln];
  float w0b = conv_w[(dir*DIMM + ln+64)*3+0],w1b = conv_w[(dir*DIMM + ln+64)*3+1];
  float w2b = conv_w[(dir*DIMM + ln+64)*3+2],cbb = conv_b[dir*DIMM + ln+64];
  float xm1a=0.f, xm2a=0.f, xm1b=0.f, xm2b=0.f;
  unsigned upk[LWIN];
  #pragma unroll
  for (int l=0;l<LWIN;l++){
    int pf = qw10 + l%G1_;
    int p  = dir ? (P_-1-pf) : pf;
    size_t row = (size_t)(row0 + (l/G1_)*P_ + p);
    unsigned v = Hx[row*64 + ln];
    float xa = bits2f_((unsigned short)(v & 0xffffu));
    float xb = bits2f_((unsigned short)(v >> 16));
    float ua = fsilu_(w0a*xm2a + w1a*xm1a + w2a*xa + cba); xm2a=xm1a; xm1a=xa;
    float ub = fsilu_(w0b*xm2b + w1b*xm1b + w2b*xb + cbb); xm2b=xm1b; xm1b=xb;
    unsigned w = pkbf16_(ua, ub);
    upk[l] = w;
    *(unsigned short*)&u_lds[l][ln]    = (unsigned short)(w & 0xffffu);
    *(unsigned short*)&u_lds[l][ln+64] = (unsigned short)(w >> 16);
  }
  *(unsigned short*)&u_lds[30][ln] = 0; *(unsigned short*)&u_lds[30][ln+64] = 0;
  *(unsigned short*)&u_lds[31][ln] = 0; *(unsigned short*)&u_lds[31][ln+64] = 0;

  const int lrow = ln & 15, koff = (ln >> 4) * 8;
  const __hip_bfloat16* Wd = Wbig + (size_t)dir*144*128;
  f32x4 acc[2][9];
  #pragma unroll
  for (int rg=0;rg<2;rg++)
    #pragma unroll
    for (int t=0;t<9;t++) acc[rg][t] = f32x4{0.f,0.f,0.f,0.f};
  #pragma unroll
  for (int kb=0; kb<4; ++kb){
    short8 av0 = *reinterpret_cast<const short8*>(&u_lds[lrow][kb*32 + koff]);
    short8 av1 = *reinterpret_cast<const short8*>(&u_lds[16 + lrow][kb*32 + koff]);
    #pragma unroll
    for (int t=0;t<9;t++){
      short8 bv = *reinterpret_cast<const short8*>(&Wd[(size_t)(t*16 + lrow)*128 + kb*32 + koff]);
      acc[0][t] = __builtin_amdgcn_mfma_f32_16x16x32_bf16(av0, bv, acc[0][t], 0,0,0);
      acc[1][t] = __builtin_amdgcn_mfma_f32_16x16x32_bf16(av1, bv, acc[1][t], 0,0,0);
    }
  }

  float dtbj[8], Avj[8];
  #pragma unroll
  for (int t=0;t<8;t++){
    int j = t*16 + lrow;
    dtbj[t] = dt_b[dir*128 + j];
    Avj[t]  = -__expf(A_log[dir*128 + j]);
  }
  float Dv0 = Dp[dir*DIMM + ln], Dv1 = Dp[dir*DIMM + ln+64];
  float h0 = 0.f, h1 = 0.f;
  unsigned* Yp = Y + ((size_t)dir*NWIN + n)*LWIN*64;
  const int loc = (ln>>4)*4;

  #pragma unroll
  for (int rg=0; rg<2; ++rg){
    #pragma unroll
    for (int t=0;t<8;t++){
      int j = t*16 + lrow;
      int wbase = ((j&63)<<1) + (j>>6);
      #pragma unroll
      for (int r=0;r<4;r++){
        float d  = fsoftplus_(acc[rg][t][r] + dtbj[t]);
        float dA = __expf(d*Avj[t]);
        es16[(loc+r)*134 + wbase] = pkbf16_(d, dA);
      }
    }
    if (lrow == 0){
      #pragma unroll
      for (int r=0;r<4;r++) Bs_[rg*16 + loc + r] = acc[rg][8][r];
    } else if (lrow == 1){
      #pragma unroll
      for (int r=0;r<4;r++) Cs_[rg*16 + loc + r] = acc[rg][8][r];
    }
    const int lst = rg*16, len = rg ? 14 : 16;
    const uint2* esr = (const uint2*)es16;
    for (int li=0; li<len; ++li){
      int l = lst + li;
      uint2 e = esr[li*67 + ln];
      float Bl = Bs_[l], Cl = Cs_[l];
      float u0 = bits2f_((unsigned short)(upk[l] & 0xffffu));
      float u1 = bits2f_((unsigned short)(upk[l] >> 16));
      float dl0 = bits2f_((unsigned short)(e.x & 0xffffu)), dA0 = bits2f_((unsigned short)(e.x >> 16));
      float dl1 = bits2f_((unsigned short)(e.y & 0xffffu)), dA1 = bits2f_((unsigned short)(e.y >> 16));
      h0 = fmaf(dA0, h0, dl0*u0*Bl);
      h1 = fmaf(dA1, h1, dl1*u1*Bl);
      float y0 = fmaf(h0, Cl, u0*Dv0);
      float y1 = fmaf(h1, Cl, u1*Dv1);
      Yp[l*64 + ln] = pkbf16_(y0, y1);
    }
  }
}

// ================= _wrev scramble index =================
__device__ __forceinline__ int win_index(int t, int p){
  int G  = t*P_ + p;
  int d3 = G / 6000;
  int r  = G % 6000;
  int d1 = r / 6;
  int r2 = r % 6;
  int d4 = r2 >> 1;
  int d2 = r2 & 1;
  int F  = d1*60 + d2*30 + d3*3 + d4;
  int a  = F / 30000;
  int F2 = F % 30000;
  int qw = F2 / 30;
  int l  = F2 % 30;
  return (a*1000 + qw)*LWIN + l;
}

// ========== out_proj GEMM: A = 0.5*(Yf+Yb_gathered)*silu(z from Hz) ; bf16 out ==========
__global__ __launch_bounds__(256) void k_gemm_out(
    const unsigned* __restrict__ Y32, const unsigned* __restrict__ Hz32,
    const __hip_bfloat16* __restrict__ Wb, __hip_bfloat16* __restrict__ yproj)
{
  __shared__ __hip_bfloat16 As[96][136];
  __shared__ __hip_bfloat16 Bs[128][136];
  const int tid = threadIdx.x;
  const size_t m0 = (size_t)blockIdx.x * 96;
  const unsigned* Yb32 = Y32 + (size_t)NWIN*LWIN*64;
  #pragma unroll
  for (int p = 0; p < 6; ++p) {
    int ch = tid + p*256; int r = ch >> 4, c16 = ch & 15;
    int token = (int)m0 + r;
    int b = token/60000, rem = token%60000, t = rem/10000, pp = rem%10000;
    size_t bbase = (size_t)b*60000;
    int wf = win_index(t, pp), wb = win_index(t, P_-1-pp);
    uint4 hzv = *reinterpret_cast<const uint4*>(&Hz32[(size_t)token*64 + c16*4]);
    uint4 fv = *reinterpret_cast<const uint4*>(&Y32 [(bbase+wf)*64 + c16*4]);
    uint4 gv = *reinterpret_cast<const uint4*>(&Yb32[(bbase+wb)*64 + c16*4]);
    const unsigned* hz = reinterpret_cast<const unsigned*>(&hzv);
    const unsigned* fu = reinterpret_cast<const unsigned*>(&fv);
    const unsigned* gu = reinterpret_cast<const unsigned*>(&gv);
    unsigned short lo[4], hi[4];
    #pragma unroll
    for (int k=0;k<4;k++){
      float zl = fsilu_(bits2f_((unsigned short)(hz[k] & 0xffffu)));
      float zh = fsilu_(bits2f_((unsigned short)(hz[k] >> 16)));
      float fl = bits2f_((unsigned short)(fu[k] & 0xffffu));
      float fh = bits2f_((unsigned short)(fu[k] >> 16));
      float gl = bits2f_((unsigned short)(gu[k] & 0xffffu));
      float gh = bits2f_((unsigned short)(gu[k] >> 16));
      lo[k] = bf16bits_(0.5f*(fl+gl)*zl);
      hi[k] = bf16bits_(0.5f*(fh+gh)*zh);
    }
    unsigned oL[2] = { (((unsigned)lo[1])<<16)|lo[0], (((unsigned)lo[3])<<16)|lo[2] };
    unsigned oH[2] = { (((unsigned)hi[1])<<16)|hi[0], (((unsigned)hi[3])<<16)|hi[2] };
    *reinterpret_cast<uint2*>(&As[r][c16*4])      = *reinterpret_cast<uint2*>(oL);
    *reinterpret_cast<uint2*>(&As[r][64 + c16*4]) = *reinterpret_cast<uint2*>(oH);
  }
  #pragma unroll
  for (int p = 0; p < 8; ++p) {
    int ch = tid + p*256; int r = ch >> 4, c16 = ch & 15;
    *reinterpret_cast<uint4*>(&Bs[r][c16*8]) =
      *reinterpret_cast<const uint4*>(&Wb[(size_t)r*128 + c16*8]);
  }
  __syncthreads();
  const int wave = tid >> 6, lane = tid & 63;
  const int rb = (wave >> 1) * 48, cb = (wave & 1) * 64;
  const int lrow = lane & 15, koff = (lane >> 4) * 8;
  f32x4 acc[3][4];
  #pragma unroll
  for (int i=0;i<3;i++)
    #pragma unroll
    for (int j=0;j<4;j++) acc[i][j] = f32x4{0.f,0.f,0.f,0.f};
  #pragma unroll
  for (int kb = 0; kb < 4; ++kb) {
    short8 a[3], bf[4];
    #pragma unroll
    for (int i=0;i<3;i++) a[i] = *reinterpret_cast<const short8*>(&As[rb + i*16 + lrow][kb*32 + koff]);
    #pragma unroll
    for (int j=0;j<4;j++) bf[j] = *reinterpret_cast<const short8*>(&Bs[cb + j*16 + lrow][kb*32 + koff]);
    #pragma unroll
    for (int i=0;i<3;i++)
      #pragma unroll
      for (int j=0;j<4;j++)
        acc[i][j] = __builtin_amdgcn_mfma_f32_16x16x32_bf16(a[i], bf[j], acc[i][j], 0,0,0);
  }
  const int crow0 = (lane >> 4) * 4, ccol = lane & 15;
  #pragma unroll
  for (int i=0;i<3;i++)
    #pragma unroll
    for (int j=0;j<4;j++){
      int nn = cb + j*16 + ccol;
      #pragma unroll
      for (int r=0;r<4;r++){
        size_t m = m0 + rb + i*16 + crow0 + r;
        yproj[m*128 + nn] = __float2bfloat16(acc[i][j][r]);
      }
    }
}

// ================= mid: x1 = xs + yproj (bf16) ; A2 = [LN(x1)|ss|·] =================
__global__ __launch_bounds__(256) void k_mid(
    const float* __restrict__ x, const float* __restrict__ xst,
    const int* __restrict__ curves, const __hip_bfloat16* __restrict__ yproj,
    __hip_bfloat16* __restrict__ x1, __hip_bfloat16* __restrict__ A2)
{
  int token = blockIdx.x*4 + (threadIdx.x>>6);
  int lane = threadIdx.x & 63;
  int b = token/60000, rem = token%60000, t = rem/10000, i = rem%10000;
  int c0 = curves[b*2*P_ + i];
  size_t src = ((size_t)(b*T_+t))*P_ + c0;
  float2 v = *reinterpret_cast<const float2*>(&x[src*128 + lane*2]);
  __hip_bfloat162 yp = *reinterpret_cast<const __hip_bfloat162*>(&yproj[(size_t)token*128 + lane*2]);
  v.x += __bfloat162float(yp.x); v.y += __bfloat162float(yp.y);
  *reinterpret_cast<unsigned*>(&x1[(size_t)token*128 + lane*2]) = pkbf16_(v.x, v.y);
  float s = v.x+v.y, q = v.x*v.x+v.y*v.y;
  #pragma unroll
  for (int d=1;d<64;d<<=1){ s += __shfl_xor(s,d); q += __shfl_xor(q,d); }
  float m = s*(1.f/128.f), var = q*(1.f/128.f)-m*m, rs = rsqrtf(var+1e-5f);
  size_t rowb = (size_t)token*KEXT;
  *reinterpret_cast<unsigned*>(&A2[rowb + lane*2]) = pkbf16_((v.x-m)*rs, (v.y-m)*rs);
  if (lane < 16) A2[rowb + 128 + lane] = __float2bfloat16(xst[src*16+lane]);
}

// ================= fused MLP: x2 = bf16(x1 + fc2(gelu(fc1e(A2)))) =================
__global__ __launch_bounds__(256) void k_gemm_mlp(
    const __hip_bfloat16* __restrict__ A, const __hip_bfloat16* __restrict__ W1e,
    const __hip_bfloat16* __restrict__ W2,
    const float* __restrict__ b1e, const float* __restrict__ b2,
    const __hip_bfloat16* __restrict__ x1, __hip_bfloat16* __restrict__ x2)
{
  __shared__ __hip_bfloat16 As[96][168];
  __shared__ __hip_bfloat16 Bs[128][168];
  const int tid = threadIdx.x;
  const size_t m0 = (size_t)blockIdx.x * 96;
  #pragma unroll
  for (int p = 0; p < 8; ++p) {
    int ch = tid + p*256;
    if (ch < 1920) {
      int r = ch/20, c8 = ch%20;
      *reinterpret_cast<uint4*>(&As[r][c8*8]) =
        *reinterpret_cast<const uint4*>(&A[(m0 + r)*KEXT + c8*8]);
    }
  }
  #pragma unroll
  for (int p = 0; p < 10; ++p) {
    int ch = tid + p*256;
    int r = ch/20, c8 = ch%20;
    *reinterpret_cast<uint4*>(&Bs[r][c8*8]) =
      *reinterpret_cast<const uint4*>(&W1e[(size_t)r*KEXT + c8*8]);
  }
  __syncthreads();
  const int wave = tid >> 6, lane = tid & 63;
  const int rb = (wave >> 1) * 48, cb = (wave & 1) * 64;
  const int lrow = lane & 15, koff = (lane >> 4) * 8;
  const int crow0 = (lane >> 4) * 4, ccol = lane & 15;
  f32x4 acc[3][4];
  #pragma unroll
  for (int i=0;i<3;i++)
    #pragma unroll
    for (int j=0;j<4;j++) acc[i][j] = f32x4{0.f,0.f,0.f,0.f};
  #pragma unroll
  for (int kb = 0; kb < 5; ++kb) {
    short8 a[3], bf[4];
    #pragma unroll
    for (int i=0;i<3;i++) a[i] = *reinterpret_cast<const short8*>(&As[rb + i*16 + lrow][kb*32 + koff]);
    #pragma unroll
    for (int j=0;j<4;j++) bf[j] = *reinterpret_cast<const short8*>(&Bs[cb + j*16 + lrow][kb*32 + koff]);
    #pragma unroll
    for (int i=0;i<3;i++)
      #pragma unroll
      for (int j=0;j<4;j++)
        acc[i][j] = __builtin_amdgcn_mfma_f32_16x16x32_bf16(a[i], bf[j], acc[i][j], 0,0,0);
  }
  __syncthreads();
  #pragma unroll
  for (int i=0;i<3;i++)
    #pragma unroll
    for (int j=0;j<4;j++){
      int nn = cb + j*16 + ccol;
      float bv = b1e[nn];
      #pragma unroll
      for (int r=0;r<4;r++){
        int row = rb + i*16 + crow0 + r;
        As[row][nn] = __float2bfloat16(geluf_(acc[i][j][r] + bv));
      }
    }
  #pragma unroll
  for (int p = 0; p < 8; ++p) {
    int ch = tid + p*256; int r = ch >> 4, c16 = ch & 15;
    *reinterpret_cast<uint4*>(&Bs[r][c16*8]) =
      *reinterpret_cast<const uint4*>(&W2[(size_t)r*128 + c16*8]);
  }
  __syncthreads();
  #pragma unroll
  for (int i=0;i<3;i++)
    #pragma unroll
    for (int j=0;j<4;j++) acc[i][j] = f32x4{0.f,0.f,0.f,0.f};
  #pragma unroll
  for (int kb = 0; kb < 4; ++kb) {
    short8 a[3], bf[4];
    #pragma unroll
    for (int i=0;i<3;i++) a[i] = *reinterpret_cast<const short8*>(&As[rb + i*16 + lrow][kb*32 + koff]);
    #pragma unroll
    for (int j=0;j<4;j++) bf[j] = *reinterpret_cast<const short8*>(&Bs[cb + j*16 + lrow][kb*32 + koff]);
    #pragma unroll
    for (int i=0;i<3;i++)
      #pragma unroll
      for (int j=0;j<4;j++)
        acc[i][j] = __builtin_amdgcn_mfma_f32_16x16x32_bf16(a[i], bf[j], acc[i][j], 0,0,0);
  }
  #pragma unroll
  for (int i=0;i<3;i++)
    #pragma unroll
    for (int j=0;j<4;j++){
      int nn = cb + j*16 + ccol;
      float bv = b2[nn];
      #pragma unroll
      for (int r=0;r<4;r++){
        size_t m = m0 + rb + i*16 + crow0 + r;
        x2[m*128 + nn] = __float2bfloat16(acc[i][j][r] + bv + __bfloat162float(x1[m*128 + nn]));
      }
    }
}

// ================= final: gather x2 by c1 -> f32 out =================
__global__ __launch_bounds__(256) void k_final(
    const __hip_bfloat16* __restrict__ x2, const int* __restrict__ curves,
    float* __restrict__ out)
{
  int token = blockIdx.x*4 + (threadIdx.x>>6);
  int lane = threadIdx.x & 63;
  int b = token/60000, rem = token%60000, t = rem/10000, i = rem%10000;
  int c1 = curves[(b*2+1)*P_ + i];
  size_t src = ((size_t)(b*T_+t))*P_ + c1;
  __hip_bfloat162 v = *reinterpret_cast<const __hip_bfloat162*>(&x2[src*128 + lane*2]);
  float2 o; o.x = __bfloat162float(v.x); o.y = __bfloat162float(v.y);
  *reinterpret_cast<float2*>(&out[(size_t)token*128 + lane*2]) = o;
}

extern "C" void kernel_launch(void* const* d_in, const int* in_sizes, int n_in,
                              void* d_out, int out_size, void* d_ws, size_t ws_size,
                              hipStream_t stream) {
  const float* x        = (const float*)d_in[0];
  const float* xst      = (const float*)d_in[1];
  const int*   curves   = (const int*)  d_in[2];
  const float* loan1_w  = (const float*)d_in[3];
  const float* loan1_b  = (const float*)d_in[4];
  const float* loan2_w  = (const float*)d_in[5];
  const float* loan2_b  = (const float*)d_in[6];
  const float* in_proj_w  = (const float*)d_in[7];
  const float* out_proj_w = (const float*)d_in[8];
  const float* conv_w   = (const float*)d_in[9];
  const float* conv_b   = (const float*)d_in[10];
  const float* xproj_w  = (const float*)d_in[11];
  const float* dt_w     = (const float*)d_in[12];
  const float* dt_b     = (const float*)d_in[13];
  const float* A_log    = (const float*)d_in[14];
  const float* Dvec     = (const float*)d_in[15];
  const float* fc1_w    = (const float*)d_in[16];
  const float* fc1_b    = (const float*)d_in[17];
  const float* fc2_w    = (const float*)d_in[18];
  const float* fc2_b    = (const float*)d_in[19];
  float* out = (float*)d_out;

  char* ws = (char*)d_ws;
  unsigned*       Ybuf = (unsigned*)(ws + 0);
  __hip_bfloat16* x1   = (__hip_bfloat16*)(ws + 0);
  unsigned*       Hx   = (unsigned*)(ws + 61440000);
  __hip_bfloat16* yproj= (__hip_bfloat16*)(ws + 61440000);
  unsigned*       Hz   = (unsigned*)(ws + 92160000);
  __hip_bfloat16* x2   = (__hip_bfloat16*)(ws + 92160000);
  __hip_bfloat16* A1   = (__hip_bfloat16*)(ws + 122880000);
  __hip_bfloat16* A2   = (__hip_bfloat16*)(ws + 122880000);
  __hip_bfloat16* wbuf = (__hip_bfloat16*)(ws + 161280000);
  __hip_bfloat16* ipw_e  = wbuf;
  __hip_bfloat16* opw_bf = wbuf + 40960;
  __hip_bfloat16* f1w_e  = wbuf + 57344;
  __hip_bfloat16* f2w_bf = wbuf + 77824;
  __hip_bfloat16* Wbig   = wbuf + 94208;
  float* biasf = (float*)(wbuf + 131072);
  float* bias_in = biasf;
  float* bias_f1 = biasf + 256;

  k_prep<<<NTOK/4 + 514, 256, 0, stream>>>(x, xst, curves, A1,
      in_proj_w, out_proj_w, fc1_w, fc2_w, xproj_w, dt_w,
      loan1_w, loan2_w, loan1_b, loan2_b, fc1_b, wbuf);

  dim3 g1(NTOK/96, 2);
  k_gemm_in<<<g1, 256, 0, stream>>>(A1, ipw_e, bias_in,
                                    (unsigned short*)Hx, (unsigned short*)Hz);

  k_scan<<<2000, 256, 0, stream>>>(Hx, conv_w, conv_b, Wbig, dt_b, A_log, Dvec, Ybuf);

  k_gemm_out<<<NTOK/96, 256, 0, stream>>>(Ybuf, Hz, opw_bf, yproj);

  k_mid<<<NTOK/4, 256, 0, stream>>>(x, xst, curves, yproj, x1, A2);

  k_gemm_mlp<<<NTOK/96, 256, 0, stream>>>(A2, f1w_e, f2w_bf, bias_f1, fc2_b, x1, x2);

  k_final<<<NTOK/4, 256, 0, stream>>>(x2, curves, out);
}